// Round 7
// baseline (815.680 us; speedup 1.0000x reference)
//
#include <hip/hip_runtime.h>
#include <hip/hip_fp16.h>
#include <math.h>

#define N_NODES 50000
#define N_EDGES 300000
#define E_TOT (N_EDGES + N_NODES)
#define IN_CH 128
#define HIDDEN 64
#define OUT_CH 40
#define NUM_LAYERS 4
#define NCHUNK ((N_NODES + 255) / 256)  // 196
#define NTILES (N_NODES / 16)           // 3125 (exact)
#define QKV_WPR 512                     // waves per role in k_qkv_mfma
#define EDGE_SLOTS 2048                 // dst-slots per head in k_edge_hm
// heads = 8, d_head = 8, scale = 1/sqrt(8)

typedef _Float16 h8 __attribute__((ext_vector_type(8)));
typedef float f32x4 __attribute__((ext_vector_type(4)));

#define MFMA16(a, b, c) __builtin_amdgcn_mfma_f32_16x16x32_f16((a), (b), (c), 0, 0, 0)

__global__ void k_count_init(int* count, int* fill) {
    int n = blockIdx.x * blockDim.x + threadIdx.x;
    if (n < N_NODES) { count[n] = 1; fill[n] = 1; }  // slot 0 = self-loop
}

__global__ void k_count(const int* __restrict__ dst, int* count) {
    int e = blockIdx.x * blockDim.x + threadIdx.x;
    if (e < N_EDGES) atomicAdd(&count[dst[e]], 1);
}

__global__ __launch_bounds__(256) void k_scan_a(const int* __restrict__ count,
                                                int* __restrict__ loc,
                                                int* __restrict__ psum) {
    __shared__ int s[256];
    int tid = threadIdx.x;
    int g = blockIdx.x * 256 + tid;
    int v = (g < N_NODES) ? count[g] : 0;
    s[tid] = v;
    __syncthreads();
    for (int off = 1; off < 256; off <<= 1) {
        int t = (tid >= off) ? s[tid - off] : 0;
        __syncthreads();
        s[tid] += t;
        __syncthreads();
    }
    if (g < N_NODES) loc[g] = s[tid] - v;  // exclusive
    if (tid == 255) psum[blockIdx.x] = s[255];
}

__global__ __launch_bounds__(256) void k_scan_b(int* psum) {
    __shared__ int s[256];
    int tid = threadIdx.x;
    int v = (tid < NCHUNK) ? psum[tid] : 0;
    s[tid] = v;
    __syncthreads();
    for (int off = 1; off < 256; off <<= 1) {
        int t = (tid >= off) ? s[tid - off] : 0;
        __syncthreads();
        s[tid] += t;
        __syncthreads();
    }
    if (tid < NCHUNK) psum[tid] = s[tid] - v;  // exclusive
}

__global__ void k_scan_c(const int* __restrict__ count, const int* __restrict__ loc,
                         const int* __restrict__ psum, int* __restrict__ rowptr,
                         float* __restrict__ dinv, int* __restrict__ ssrc,
                         float* __restrict__ snorm) {
    int n = blockIdx.x * blockDim.x + threadIdx.x;
    if (n >= N_NODES) return;
    int rp = loc[n] + psum[n >> 8];
    rowptr[n] = rp;
    float di = rsqrtf((float)count[n]);
    dinv[n] = di;
    ssrc[rp] = n;           // self-loop edge
    snorm[rp] = di * di;
    if (n == 0) rowptr[N_NODES] = E_TOT;
}

__global__ void k_scatter(const int* __restrict__ ei, const int* __restrict__ rowptr,
                          int* __restrict__ fill, const float* __restrict__ dinv,
                          int* __restrict__ ssrc, float* __restrict__ snorm) {
    int e = blockIdx.x * blockDim.x + threadIdx.x;
    if (e >= N_EDGES) return;
    int s = ei[e], d = ei[N_EDGES + e];
    int p = rowptr[d] + atomicAdd(&fill[d], 1);
    ssrc[p] = s;
    snorm[p] = dinv[s] * dinv[d];
}

__device__ __forceinline__ h8 load_bfrag(const float* __restrict__ W, int ncols,
                                         int kbase, int c) {
    h8 r;
#pragma unroll
    for (int i = 0; i < 8; ++i) r[i] = (_Float16)W[(kbase + i) * ncols + c];
    return r;
}

__device__ __forceinline__ void unpack8(float4 raw, float* f) {
    const __half2* hp = (const __half2*)&raw;
#pragma unroll
    for (int i = 0; i < 4; ++i) {
        float2 t = __half22float2(hp[i]);
        f[2 * i] = t.x;
        f[2 * i + 1] = t.y;
    }
}

// h = relu(x @ w1 + b1) -> xh[:,0,:] (fp16), via MFMA.
__global__ __launch_bounds__(256) void k_h_mfma(const float* __restrict__ x,
                                                const float* __restrict__ w1,
                                                const float* __restrict__ b1,
                                                __half* __restrict__ xh) {
    int lane = threadIdx.x & 63;
    int gw = blockIdx.x * 4 + (threadIdx.x >> 6);
    int krow = lane >> 4, col = lane & 15;
    h8 B[4][4];
#pragma unroll
    for (int ct = 0; ct < 4; ++ct)
#pragma unroll
        for (int s = 0; s < 4; ++s)
            B[ct][s] = load_bfrag(w1, HIDDEN, krow * 8 + 32 * s, ct * 16 + col);
    float bias[4];
#pragma unroll
    for (int ct = 0; ct < 4; ++ct) bias[ct] = b1[ct * 16 + col];
    for (int t = gw; t < NTILES; t += 1024) {
        int n0 = t * 16;
        const float* xrow = x + (size_t)(n0 + col) * IN_CH + krow * 8;
        f32x4 acc[4] = {{0.f, 0.f, 0.f, 0.f}, {0.f, 0.f, 0.f, 0.f},
                        {0.f, 0.f, 0.f, 0.f}, {0.f, 0.f, 0.f, 0.f}};
#pragma unroll
        for (int s = 0; s < 4; ++s) {
            float4 p0 = *(const float4*)(xrow + 32 * s);
            float4 p1 = *(const float4*)(xrow + 32 * s + 4);
            h8 a;
            a[0] = (_Float16)p0.x; a[1] = (_Float16)p0.y;
            a[2] = (_Float16)p0.z; a[3] = (_Float16)p0.w;
            a[4] = (_Float16)p1.x; a[5] = (_Float16)p1.y;
            a[6] = (_Float16)p1.z; a[7] = (_Float16)p1.w;
#pragma unroll
            for (int ct = 0; ct < 4; ++ct) acc[ct] = MFMA16(a, B[ct][s], acc[ct]);
        }
#pragma unroll
        for (int ct = 0; ct < 4; ++ct)
#pragma unroll
            for (int reg = 0; reg < 4; ++reg) {
                float v = fmaxf(acc[ct][reg] + bias[ct], 0.f);
                xh[(size_t)(n0 + krow * 4 + reg) * 320 + ct * 16 + col] = __float2half(v);
            }
    }
}

// Layer-1 v-only projection (softmax over L=1 is identically 1; q,k unused).
// Output channel-major vh1[n][64] fp16.
__global__ __launch_bounds__(256) void k_v1_mfma(const __half* __restrict__ xh,
                                                 const float* __restrict__ wv,
                                                 __half* __restrict__ vh1) {
    int lane = threadIdx.x & 63;
    int gw = blockIdx.x * 4 + (threadIdx.x >> 6);
    int krow = lane >> 4, col = lane & 15;
    h8 B[4][2];
#pragma unroll
    for (int ct = 0; ct < 4; ++ct)
#pragma unroll
        for (int s = 0; s < 2; ++s)
            B[ct][s] = load_bfrag(wv, HIDDEN, krow * 8 + 32 * s, ct * 16 + col);
    for (int t = gw; t < NTILES; t += QKV_WPR) {
        int n0 = t * 16;
        const __half* ap = xh + (size_t)(n0 + col) * 320 + krow * 8;  // row 0
        h8 a0 = *(const h8*)(const void*)ap;
        h8 a1 = *(const h8*)(const void*)(ap + 32);
        f32x4 acc[4] = {{0.f, 0.f, 0.f, 0.f}, {0.f, 0.f, 0.f, 0.f},
                        {0.f, 0.f, 0.f, 0.f}, {0.f, 0.f, 0.f, 0.f}};
#pragma unroll
        for (int ct = 0; ct < 4; ++ct) {
            acc[ct] = MFMA16(a0, B[ct][0], acc[ct]);
            acc[ct] = MFMA16(a1, B[ct][1], acc[ct]);
        }
#pragma unroll
        for (int ct = 0; ct < 4; ++ct)
#pragma unroll
            for (int reg = 0; reg < 4; ++reg)
                vh1[(size_t)(n0 + krow * 4 + reg) * 64 + ct * 16 + col] =
                    __float2half(acc[ct][reg]);
    }
}

// Layer-1 edge kernel: pure normalized SpMV over vh1. 8 edges/wave, lane r owns
// channels 8r..8r+7. Output -> xh row 1.
__global__ __launch_bounds__(256) void k_edge_l1(const int* __restrict__ rowptr,
                                                 const int* __restrict__ ssrc,
                                                 const float* __restrict__ snorm,
                                                 const __half* __restrict__ vh1,
                                                 __half* __restrict__ xh) {
    int tid = threadIdx.x;
    int wid = tid >> 6, lane = tid & 63;
    int g = lane >> 3, r = lane & 7;
    int d = blockIdx.x * 4 + wid;
    if (d >= N_NODES) return;
    int rs = rowptr[d], re = rowptr[d + 1];
    float acc[8];
#pragma unroll
    for (int i = 0; i < 8; ++i) acc[i] = 0.f;
    for (int base = rs; base < re; base += 8) {
        int eidx = base + g;
        bool valid = eidx < re;
        int s = valid ? ssrc[eidx] : 0;
        float nrm = valid ? snorm[eidx] : 0.f;
        float4 raw = *(const float4*)(vh1 + (size_t)s * 64 + r * 8);
        float f[8];
        unpack8(raw, f);
#pragma unroll
        for (int c = 0; c < 8; ++c) acc[c] = fmaf(nrm, f[c], acc[c]);
    }
#pragma unroll
    for (int c = 0; c < 8; ++c) {
        acc[c] += __shfl_xor(acc[c], 8);
        acc[c] += __shfl_xor(acc[c], 16);
        acc[c] += __shfl_xor(acc[c], 32);
    }
    if (lane < 8) {
        __half hbuf[8];
#pragma unroll
        for (int c = 0; c < 8; ++c) hbuf[c] = __float2half(fmaxf(acc[c], 0.f));
        *(float4*)(xh + (size_t)d * 320 + 64 + r * 8) = *(float4*)hbuf;
    }
}

// q / merged-kv projections via MFMA (L>=2). role 0: q (row L-1, pre-scaled);
// roles 1..L: k & v for row role-1, stored HEAD-MAJOR:
// kvh[((h*N + n)*L + lx)*16 + j*8 + c]  (j=0 k, j=1 v), 32 B per (h,n,lx).
template <int L>
__global__ __launch_bounds__(256) void k_qkv_mfma(const __half* __restrict__ xh,
                                                  const float* __restrict__ wq,
                                                  const float* __restrict__ wk,
                                                  const float* __restrict__ wv,
                                                  __half* __restrict__ qh,
                                                  __half* __restrict__ kvh) {
    int lane = threadIdx.x & 63;
    int gw = blockIdx.x * 4 + (threadIdx.x >> 6);
    int role = gw / QKV_WPR;
    int slot = gw - role * QKV_WPR;
    int krow = lane >> 4, col = lane & 15;
    if (role == 0) {
        int lx = L - 1;
        h8 B[4][2];
#pragma unroll
        for (int ct = 0; ct < 4; ++ct)
#pragma unroll
            for (int s = 0; s < 2; ++s)
                B[ct][s] = load_bfrag(wq, HIDDEN, krow * 8 + 32 * s, ct * 16 + col);
        for (int t = slot; t < NTILES; t += QKV_WPR) {
            int n0 = t * 16;
            const __half* ap = xh + (size_t)(n0 + col) * 320 + lx * 64 + krow * 8;
            h8 a0 = *(const h8*)(const void*)ap;
            h8 a1 = *(const h8*)(const void*)(ap + 32);
            f32x4 acc[4] = {{0.f, 0.f, 0.f, 0.f}, {0.f, 0.f, 0.f, 0.f},
                            {0.f, 0.f, 0.f, 0.f}, {0.f, 0.f, 0.f, 0.f}};
#pragma unroll
            for (int ct = 0; ct < 4; ++ct) {
                acc[ct] = MFMA16(a0, B[ct][0], acc[ct]);
                acc[ct] = MFMA16(a1, B[ct][1], acc[ct]);
            }
#pragma unroll
            for (int ct = 0; ct < 4; ++ct)
#pragma unroll
                for (int reg = 0; reg < 4; ++reg)
                    qh[(size_t)(n0 + krow * 4 + reg) * 64 + ct * 16 + col] =
                        __float2half(acc[ct][reg] * 0.35355339059327373f);
        }
    } else {
        int lx = role - 1;
        h8 Bk[4][2], Bv[4][2];
#pragma unroll
        for (int ct = 0; ct < 4; ++ct)
#pragma unroll
            for (int s = 0; s < 2; ++s) {
                Bk[ct][s] = load_bfrag(wk, HIDDEN, krow * 8 + 32 * s, ct * 16 + col);
                Bv[ct][s] = load_bfrag(wv, HIDDEN, krow * 8 + 32 * s, ct * 16 + col);
            }
        for (int t = slot; t < NTILES; t += QKV_WPR) {
            int n0 = t * 16;
            const __half* ap = xh + (size_t)(n0 + col) * 320 + lx * 64 + krow * 8;
            h8 a0 = *(const h8*)(const void*)ap;
            h8 a1 = *(const h8*)(const void*)(ap + 32);
            f32x4 ak[4] = {{0.f, 0.f, 0.f, 0.f}, {0.f, 0.f, 0.f, 0.f},
                           {0.f, 0.f, 0.f, 0.f}, {0.f, 0.f, 0.f, 0.f}};
            f32x4 av[4] = {{0.f, 0.f, 0.f, 0.f}, {0.f, 0.f, 0.f, 0.f},
                           {0.f, 0.f, 0.f, 0.f}, {0.f, 0.f, 0.f, 0.f}};
#pragma unroll
            for (int ct = 0; ct < 4; ++ct) {
                ak[ct] = MFMA16(a0, Bk[ct][0], ak[ct]);
                ak[ct] = MFMA16(a1, Bk[ct][1], ak[ct]);
                av[ct] = MFMA16(a0, Bv[ct][0], av[ct]);
                av[ct] = MFMA16(a1, Bv[ct][1], av[ct]);
            }
#pragma unroll
            for (int ct = 0; ct < 4; ++ct)
#pragma unroll
                for (int reg = 0; reg < 4; ++reg) {
                    int n = n0 + krow * 4 + reg;
                    int ch = ct * 16 + col;
                    int h = ch >> 3, c = ch & 7;
                    size_t base = (((size_t)h * N_NODES + n) * L + lx) * 16 + c;
                    kvh[base] = __float2half(ak[ct][reg]);
                    kvh[base + 8] = __float2half(av[ct][reg]);
                }
        }
    }
}

// Head-partitioned CSR edge kernel (L>=2). head = blockIdx & 7 (XCD round-robin
// pins each head's kvh slice to one XCD's L2). Subgroup of 2L lanes per edge:
// lane sub = 2l+j loads 16 B (j=0: k, j=1: v) of (head, src, l). Scores shared
// via bpermute; message reduced by full-wave xor shuffles.
template <int L>
__global__ __launch_bounds__(256) void k_edge_hm(const int* __restrict__ rowptr,
                                                 const int* __restrict__ ssrc,
                                                 const float* __restrict__ snorm,
                                                 const __half* __restrict__ kvh,
                                                 const __half* __restrict__ qh,
                                                 float* __restrict__ aggout,
                                                 __half* __restrict__ xh) {
    constexpr int S = (L == 2) ? 4 : 8;  // subgroup size (pow2 >= 2L)
    constexpr int E = 64 / S;            // edges per wave
    int tid = threadIdx.x;
    int wid = tid >> 6, lane = tid & 63;
    int h = blockIdx.x & 7;
    int slot = blockIdx.x >> 3;
    int g = lane / S, sub = lane & (S - 1);
    int l = sub >> 1, j = sub & 1;
    int lc = (l < L) ? l : (L - 1);
    int sgbase = lane & ~(S - 1);
    for (int d = slot * 4 + wid; d < N_NODES; d += EDGE_SLOTS * 4) {
        int rs = rowptr[d], re = rowptr[d + 1];
        float qf[8];
        unpack8(*(const float4*)(qh + (size_t)d * 64 + h * 8), qf);
        float acc[8];
#pragma unroll
        for (int c = 0; c < 8; ++c) acc[c] = 0.f;
        for (int base = rs; base < re; base += E) {
            int eidx = base + g;
            bool valid = eidx < re;
            int s = valid ? ssrc[eidx] : 0;
            float nrm = valid ? snorm[eidx] : 0.f;
            float4 raw = *(const float4*)(
                kvh + ((((size_t)h * N_NODES + s) * L + lc) * 2 + j) * 8);
            float f[8];
            unpack8(raw, f);
            float p = 0.f;
#pragma unroll
            for (int c = 0; c < 8; ++c) p = fmaf(qf[c], f[c], p);
            float sc[L];
            float m = -1e30f;
#pragma unroll
            for (int ll = 0; ll < L; ++ll) {
                sc[ll] = __shfl(p, sgbase + 2 * ll, 64);
                m = fmaxf(m, sc[ll]);
            }
            float ssum = 0.f;
#pragma unroll
            for (int ll = 0; ll < L; ++ll) {
                sc[ll] = __expf(sc[ll] - m);
                ssum += sc[ll];
            }
            float w = __fdividef(nrm, ssum);
            float my_e = 0.f;
#pragma unroll
            for (int ll = 0; ll < L; ++ll) my_e = (l == ll) ? sc[ll] : my_e;
            float a = (j == 1 && l < L) ? my_e * w : 0.f;
#pragma unroll
            for (int c = 0; c < 8; ++c) acc[c] = fmaf(a, f[c], acc[c]);
        }
#pragma unroll
        for (int c = 0; c < 8; ++c) {
            acc[c] += __shfl_xor(acc[c], 1);
            acc[c] += __shfl_xor(acc[c], 2);
            acc[c] += __shfl_xor(acc[c], 4);
            acc[c] += __shfl_xor(acc[c], 8);
            acc[c] += __shfl_xor(acc[c], 16);
            acc[c] += __shfl_xor(acc[c], 32);
        }
        if (lane == 0) {
            if (L == NUM_LAYERS) {
                float4 o0, o1;
                o0.x = fmaxf(acc[0], 0.f); o0.y = fmaxf(acc[1], 0.f);
                o0.z = fmaxf(acc[2], 0.f); o0.w = fmaxf(acc[3], 0.f);
                o1.x = fmaxf(acc[4], 0.f); o1.y = fmaxf(acc[5], 0.f);
                o1.z = fmaxf(acc[6], 0.f); o1.w = fmaxf(acc[7], 0.f);
                float4* op = (float4*)(aggout + (size_t)d * 64 + h * 8);
                op[0] = o0; op[1] = o1;
            } else {
                __half hbuf[8];
#pragma unroll
                for (int c = 0; c < 8; ++c) hbuf[c] = __float2half(fmaxf(acc[c], 0.f));
                *(float4*)(xh + (size_t)d * 320 + L * 64 + h * 8) = *(float4*)hbuf;
            }
        }
    }
}

// logits = aggout @ w2 + b2; out = log_softmax(logits)
__global__ __launch_bounds__(256) void k_final_lds(const float* __restrict__ aggout,
                                                   const float* __restrict__ w2,
                                                   const float* __restrict__ b2,
                                                   float* __restrict__ out) {
    __shared__ float rows[16][HIDDEN];
    int tid = threadIdx.x, wid = tid >> 6, lane = tid & 63;
    int cl = (lane < OUT_CH) ? lane : (OUT_CH - 1);
    float wcol[HIDDEN];
#pragma unroll
    for (int j = 0; j < HIDDEN; ++j) wcol[j] = w2[j * OUT_CH + cl];
    float b = b2[cl];
    for (int t = blockIdx.x; t < NTILES; t += gridDim.x) {
        int n0 = t * 16;
        {
            int rr = tid >> 4, seg = tid & 15;
            *(float4*)&rows[rr][seg * 4] =
                *(const float4*)&aggout[(size_t)(n0 + rr) * 64 + seg * 4];
        }
        __syncthreads();
#pragma unroll
        for (int u = 0; u < 4; ++u) {
            int ln = wid * 4 + u;
            const float4* rp = (const float4*)rows[ln];
            float a0 = 0.f, a1 = 0.f, a2 = 0.f, a3 = 0.f;
#pragma unroll
            for (int jc = 0; jc < HIDDEN / 4; ++jc) {
                float4 r = rp[jc];
                a0 = fmaf(r.x, wcol[jc * 4 + 0], a0);
                a1 = fmaf(r.y, wcol[jc * 4 + 1], a1);
                a2 = fmaf(r.z, wcol[jc * 4 + 2], a2);
                a3 = fmaf(r.w, wcol[jc * 4 + 3], a3);
            }
            float logit = (lane < OUT_CH) ? ((a0 + a1) + (a2 + a3) + b) : -INFINITY;
            float m = logit;
            for (int mask = 32; mask; mask >>= 1) m = fmaxf(m, __shfl_xor(m, mask));
            float ex = (lane < OUT_CH) ? __expf(logit - m) : 0.f;
            float ssum = ex;
            for (int mask = 32; mask; mask >>= 1) ssum += __shfl_xor(ssum, mask);
            if (lane < OUT_CH)
                out[(size_t)(n0 + ln) * OUT_CH + lane] = logit - m - logf(ssum);
        }
        __syncthreads();
    }
}

extern "C" void kernel_launch(void* const* d_in, const int* in_sizes, int n_in,
                              void* d_out, int out_size, void* d_ws, size_t ws_size,
                              hipStream_t stream) {
    const float* x  = (const float*)d_in[0];
    const int*   ei = (const int*)d_in[1];
    // d_in[2] = heads (known 8)
    const float* w1 = (const float*)d_in[3];
    const float* b1 = (const float*)d_in[4];
    const float* wq = (const float*)d_in[5];
    const float* wk = (const float*)d_in[6];
    const float* wv = (const float*)d_in[7];
    const float* w2 = (const float*)d_in[8];
    const float* b2 = (const float*)d_in[9];
    float* out = (float*)d_out;

    char* cur = (char*)d_ws;
    auto alloc = [&](size_t bytes) { char* p = cur; cur += (bytes + 255) & ~(size_t)255; return p; };
    float*   dinv   = (float*)alloc(N_NODES * 4);
    __half*  xh     = (__half*)alloc((size_t)N_NODES * 320 * 2);
    float*   aggout = (float*)alloc((size_t)N_NODES * 64 * 4);
    __half*  qh     = (__half*)alloc((size_t)N_NODES * 64 * 2);
    __half*  kvh    = (__half*)alloc((size_t)8 * N_NODES * NUM_LAYERS * 16 * 2);
    __half*  vh1    = (__half*)alloc((size_t)N_NODES * 64 * 2);
    int*     count  = (int*)alloc(N_NODES * 4);
    int*     loc    = (int*)alloc(N_NODES * 4);
    int*     psum   = (int*)alloc(256 * 4);
    int*     rowptr = (int*)alloc((N_NODES + 1) * 4);
    int*     fill   = (int*)alloc(N_NODES * 4);
    int*     ssrc   = (int*)alloc((size_t)E_TOT * 4);
    float*   snorm  = (float*)alloc((size_t)E_TOT * 4);

    // CSR build (once)
    k_count_init<<<(N_NODES + 255) / 256, 256, 0, stream>>>(count, fill);
    k_count<<<(N_EDGES + 255) / 256, 256, 0, stream>>>(ei + N_EDGES, count);
    k_scan_a<<<NCHUNK, 256, 0, stream>>>(count, loc, psum);
    k_scan_b<<<1, 256, 0, stream>>>(psum);
    k_scan_c<<<(N_NODES + 255) / 256, 256, 0, stream>>>(count, loc, psum, rowptr,
                                                        dinv, ssrc, snorm);
    k_scatter<<<(N_EDGES + 255) / 256, 256, 0, stream>>>(ei, rowptr, fill, dinv,
                                                         ssrc, snorm);

    k_h_mfma<<<256, 256, 0, stream>>>(x, w1, b1, xh);

    // Layer 1 (L=1): softmax over a single slot == 1; only v matters.
    k_v1_mfma<<<QKV_WPR / 4, 256, 0, stream>>>(xh, wv, vh1);
    k_edge_l1<<<(N_NODES + 3) / 4, 256, 0, stream>>>(rowptr, ssrc, snorm, vh1, xh);

    for (int i = 1; i < NUM_LAYERS; ++i) {
        int L = i + 1;
        int qkvblk = (L + 1) * (QKV_WPR / 4);
        const float* wqi = wq + i * 4096;
        const float* wki = wk + i * 4096;
        const float* wvi = wv + i * 4096;
        switch (L) {
            case 2:
                k_qkv_mfma<2><<<qkvblk, 256, 0, stream>>>(xh, wqi, wki, wvi, qh, kvh);
                k_edge_hm<2><<<8 * EDGE_SLOTS, 256, 0, stream>>>(rowptr, ssrc, snorm, kvh, qh, aggout, xh);
                break;
            case 3:
                k_qkv_mfma<3><<<qkvblk, 256, 0, stream>>>(xh, wqi, wki, wvi, qh, kvh);
                k_edge_hm<3><<<8 * EDGE_SLOTS, 256, 0, stream>>>(rowptr, ssrc, snorm, kvh, qh, aggout, xh);
                break;
            default:
                k_qkv_mfma<4><<<qkvblk, 256, 0, stream>>>(xh, wqi, wki, wvi, qh, kvh);
                k_edge_hm<4><<<8 * EDGE_SLOTS, 256, 0, stream>>>(rowptr, ssrc, snorm, kvh, qh, aggout, xh);
                break;
        }
    }
    k_final_lds<<<512, 256, 0, stream>>>(aggout, w2, b2, out);
}

// Round 8
// 276.953 us; speedup vs baseline: 2.9452x; 2.9452x over previous
//
#include <hip/hip_runtime.h>
#include <hip/hip_fp16.h>
#include <math.h>

#define N_NODES 50000
#define N_EDGES 300000
#define E_TOT (N_EDGES + N_NODES)
#define IN_CH 128
#define HIDDEN 64
#define OUT_CH 40
#define NUM_LAYERS 4
#define NCHUNK ((N_NODES + 255) / 256)  // 196
#define NTILES (N_NODES / 16)           // 3125 (exact)
#define QKV_WPR 512                     // waves per role in k_qkv_mfma
// heads = 8, d_head = 8, scale = 1/sqrt(8)

typedef _Float16 h8 __attribute__((ext_vector_type(8)));
typedef float f32x4 __attribute__((ext_vector_type(4)));

#define MFMA16(a, b, c) __builtin_amdgcn_mfma_f32_16x16x32_f16((a), (b), (c), 0, 0, 0)

__global__ void k_count_init(int* count, int* fill) {
    int n = blockIdx.x * blockDim.x + threadIdx.x;
    if (n < N_NODES) { count[n] = 1; fill[n] = 1; }  // slot 0 = self-loop
}

__global__ void k_count(const int* __restrict__ dst, int* count) {
    int e = blockIdx.x * blockDim.x + threadIdx.x;
    if (e < N_EDGES) atomicAdd(&count[dst[e]], 1);
}

__global__ __launch_bounds__(256) void k_scan_a(const int* __restrict__ count,
                                                int* __restrict__ loc,
                                                int* __restrict__ psum) {
    __shared__ int s[256];
    int tid = threadIdx.x;
    int g = blockIdx.x * 256 + tid;
    int v = (g < N_NODES) ? count[g] : 0;
    s[tid] = v;
    __syncthreads();
    for (int off = 1; off < 256; off <<= 1) {
        int t = (tid >= off) ? s[tid - off] : 0;
        __syncthreads();
        s[tid] += t;
        __syncthreads();
    }
    if (g < N_NODES) loc[g] = s[tid] - v;  // exclusive
    if (tid == 255) psum[blockIdx.x] = s[255];
}

__global__ __launch_bounds__(256) void k_scan_b(int* psum) {
    __shared__ int s[256];
    int tid = threadIdx.x;
    int v = (tid < NCHUNK) ? psum[tid] : 0;
    s[tid] = v;
    __syncthreads();
    for (int off = 1; off < 256; off <<= 1) {
        int t = (tid >= off) ? s[tid - off] : 0;
        __syncthreads();
        s[tid] += t;
        __syncthreads();
    }
    if (tid < NCHUNK) psum[tid] = s[tid] - v;  // exclusive
}

__global__ void k_scan_c(const int* __restrict__ count, const int* __restrict__ loc,
                         const int* __restrict__ psum, int* __restrict__ rowptr,
                         float* __restrict__ dinv, int2* __restrict__ edata) {
    int n = blockIdx.x * blockDim.x + threadIdx.x;
    if (n >= N_NODES) return;
    int rp = loc[n] + psum[n >> 8];
    rowptr[n] = rp;
    float di = rsqrtf((float)count[n]);
    dinv[n] = di;
    edata[rp] = make_int2(n, __float_as_int(di * di));  // self-loop edge
    if (n == 0) rowptr[N_NODES] = E_TOT;
}

__global__ void k_scatter(const int* __restrict__ ei, const int* __restrict__ rowptr,
                          int* __restrict__ fill, const float* __restrict__ dinv,
                          int2* __restrict__ edata) {
    int e = blockIdx.x * blockDim.x + threadIdx.x;
    if (e >= N_EDGES) return;
    int s = ei[e], d = ei[N_EDGES + e];
    int p = rowptr[d] + atomicAdd(&fill[d], 1);
    edata[p] = make_int2(s, __float_as_int(dinv[s] * dinv[d]));
}

__device__ __forceinline__ h8 load_bfrag(const float* __restrict__ W, int ncols,
                                         int kbase, int c) {
    h8 r;
#pragma unroll
    for (int i = 0; i < 8; ++i) r[i] = (_Float16)W[(kbase + i) * ncols + c];
    return r;
}

__device__ __forceinline__ void unpack8(float4 raw, float* f) {
    const __half2* hp = (const __half2*)&raw;
#pragma unroll
    for (int i = 0; i < 4; ++i) {
        float2 t = __half22float2(hp[i]);
        f[2 * i] = t.x;
        f[2 * i + 1] = t.y;
    }
}

// h = relu(x @ w1 + b1) -> xh[:,0,:] (fp16), via MFMA.
__global__ __launch_bounds__(256) void k_h_mfma(const float* __restrict__ x,
                                                const float* __restrict__ w1,
                                                const float* __restrict__ b1,
                                                __half* __restrict__ xh) {
    int lane = threadIdx.x & 63;
    int gw = blockIdx.x * 4 + (threadIdx.x >> 6);
    int krow = lane >> 4, col = lane & 15;
    h8 B[4][4];
#pragma unroll
    for (int ct = 0; ct < 4; ++ct)
#pragma unroll
        for (int s = 0; s < 4; ++s)
            B[ct][s] = load_bfrag(w1, HIDDEN, krow * 8 + 32 * s, ct * 16 + col);
    float bias[4];
#pragma unroll
    for (int ct = 0; ct < 4; ++ct) bias[ct] = b1[ct * 16 + col];
    for (int t = gw; t < NTILES; t += 1024) {
        int n0 = t * 16;
        const float* xrow = x + (size_t)(n0 + col) * IN_CH + krow * 8;
        f32x4 acc[4] = {{0.f, 0.f, 0.f, 0.f}, {0.f, 0.f, 0.f, 0.f},
                        {0.f, 0.f, 0.f, 0.f}, {0.f, 0.f, 0.f, 0.f}};
#pragma unroll
        for (int s = 0; s < 4; ++s) {
            float4 p0 = *(const float4*)(xrow + 32 * s);
            float4 p1 = *(const float4*)(xrow + 32 * s + 4);
            h8 a;
            a[0] = (_Float16)p0.x; a[1] = (_Float16)p0.y;
            a[2] = (_Float16)p0.z; a[3] = (_Float16)p0.w;
            a[4] = (_Float16)p1.x; a[5] = (_Float16)p1.y;
            a[6] = (_Float16)p1.z; a[7] = (_Float16)p1.w;
#pragma unroll
            for (int ct = 0; ct < 4; ++ct) acc[ct] = MFMA16(a, B[ct][s], acc[ct]);
        }
#pragma unroll
        for (int ct = 0; ct < 4; ++ct)
#pragma unroll
            for (int reg = 0; reg < 4; ++reg) {
                float v = fmaxf(acc[ct][reg] + bias[ct], 0.f);
                xh[(size_t)(n0 + krow * 4 + reg) * 320 + ct * 16 + col] = __float2half(v);
            }
    }
}

// Layer-1 v-only projection (softmax over L=1 is identically 1; q,k unused).
__global__ __launch_bounds__(256) void k_v1_mfma(const __half* __restrict__ xh,
                                                 const float* __restrict__ wv,
                                                 __half* __restrict__ vh1) {
    int lane = threadIdx.x & 63;
    int gw = blockIdx.x * 4 + (threadIdx.x >> 6);
    int krow = lane >> 4, col = lane & 15;
    h8 B[4][2];
#pragma unroll
    for (int ct = 0; ct < 4; ++ct)
#pragma unroll
        for (int s = 0; s < 2; ++s)
            B[ct][s] = load_bfrag(wv, HIDDEN, krow * 8 + 32 * s, ct * 16 + col);
    for (int t = gw; t < NTILES; t += QKV_WPR) {
        int n0 = t * 16;
        const __half* ap = xh + (size_t)(n0 + col) * 320 + krow * 8;  // row 0
        h8 a0 = *(const h8*)(const void*)ap;
        h8 a1 = *(const h8*)(const void*)(ap + 32);
        f32x4 acc[4] = {{0.f, 0.f, 0.f, 0.f}, {0.f, 0.f, 0.f, 0.f},
                        {0.f, 0.f, 0.f, 0.f}, {0.f, 0.f, 0.f, 0.f}};
#pragma unroll
        for (int ct = 0; ct < 4; ++ct) {
            acc[ct] = MFMA16(a0, B[ct][0], acc[ct]);
            acc[ct] = MFMA16(a1, B[ct][1], acc[ct]);
        }
#pragma unroll
        for (int ct = 0; ct < 4; ++ct)
#pragma unroll
            for (int reg = 0; reg < 4; ++reg)
                vh1[(size_t)(n0 + krow * 4 + reg) * 64 + ct * 16 + col] =
                    __float2half(acc[ct][reg]);
    }
}

// Layer-1 edge kernel: pure normalized SpMV over vh1. 8 edges/wave, lane r owns
// channels 8r..8r+7. Output -> xh row 1 (relu'd fp16).
__global__ __launch_bounds__(256) void k_edge_l1(const int* __restrict__ rowptr,
                                                 const int2* __restrict__ edata,
                                                 const __half* __restrict__ vh1,
                                                 __half* __restrict__ xh) {
    int tid = threadIdx.x;
    int wid = tid >> 6, lane = tid & 63;
    int g = lane >> 3, r = lane & 7;
    int d = blockIdx.x * 4 + wid;
    if (d >= N_NODES) return;
    int rs = rowptr[d], re = rowptr[d + 1];
    float acc[8];
#pragma unroll
    for (int i = 0; i < 8; ++i) acc[i] = 0.f;
    for (int base = rs; base < re; base += 8) {
        int eidx = base + g;
        bool valid = eidx < re;
        int2 e = edata[valid ? eidx : rs];
        int s = e.x;
        float nrm = valid ? __int_as_float(e.y) : 0.f;
        float4 raw = *(const float4*)(vh1 + (size_t)s * 64 + r * 8);
        float f[8];
        unpack8(raw, f);
#pragma unroll
        for (int c = 0; c < 8; ++c) acc[c] = fmaf(nrm, f[c], acc[c]);
    }
#pragma unroll
    for (int c = 0; c < 8; ++c) {
        acc[c] += __shfl_xor(acc[c], 8);
        acc[c] += __shfl_xor(acc[c], 16);
        acc[c] += __shfl_xor(acc[c], 32);
    }
    if (lane < 8) {
        __half hbuf[8];
#pragma unroll
        for (int c = 0; c < 8; ++c) hbuf[c] = __float2half(fmaxf(acc[c], 0.f));
        *(float4*)(xh + (size_t)d * 320 + 64 + r * 8) = *(float4*)hbuf;
    }
}

// q / merged-kv projections via MFMA (L>=2). role 0: q (row L-1, pre-scaled);
// roles 1..L: k & v for row role-1, interleaved per (n,l):
// kvi[((n*L)+lx)*128 + j*64 + ch]  (j=0: k, j=1: v) -> one contiguous 256 B block.
template <int L>
__global__ __launch_bounds__(256) void k_qkv_mfma(const __half* __restrict__ xh,
                                                  const float* __restrict__ wq,
                                                  const float* __restrict__ wk,
                                                  const float* __restrict__ wv,
                                                  __half* __restrict__ qh,
                                                  __half* __restrict__ kvi) {
    int lane = threadIdx.x & 63;
    int gw = blockIdx.x * 4 + (threadIdx.x >> 6);
    int role = gw / QKV_WPR;
    int slot = gw - role * QKV_WPR;
    int krow = lane >> 4, col = lane & 15;
    if (role == 0) {
        int lx = L - 1;
        h8 B[4][2];
#pragma unroll
        for (int ct = 0; ct < 4; ++ct)
#pragma unroll
            for (int s = 0; s < 2; ++s)
                B[ct][s] = load_bfrag(wq, HIDDEN, krow * 8 + 32 * s, ct * 16 + col);
        for (int t = slot; t < NTILES; t += QKV_WPR) {
            int n0 = t * 16;
            const __half* ap = xh + (size_t)(n0 + col) * 320 + lx * 64 + krow * 8;
            h8 a0 = *(const h8*)(const void*)ap;
            h8 a1 = *(const h8*)(const void*)(ap + 32);
            f32x4 acc[4] = {{0.f, 0.f, 0.f, 0.f}, {0.f, 0.f, 0.f, 0.f},
                            {0.f, 0.f, 0.f, 0.f}, {0.f, 0.f, 0.f, 0.f}};
#pragma unroll
            for (int ct = 0; ct < 4; ++ct) {
                acc[ct] = MFMA16(a0, B[ct][0], acc[ct]);
                acc[ct] = MFMA16(a1, B[ct][1], acc[ct]);
            }
#pragma unroll
            for (int ct = 0; ct < 4; ++ct)
#pragma unroll
                for (int reg = 0; reg < 4; ++reg)
                    qh[(size_t)(n0 + krow * 4 + reg) * 64 + ct * 16 + col] =
                        __float2half(acc[ct][reg] * 0.35355339059327373f);
        }
    } else {
        int lx = role - 1;
        h8 Bk[4][2], Bv[4][2];
#pragma unroll
        for (int ct = 0; ct < 4; ++ct)
#pragma unroll
            for (int s = 0; s < 2; ++s) {
                Bk[ct][s] = load_bfrag(wk, HIDDEN, krow * 8 + 32 * s, ct * 16 + col);
                Bv[ct][s] = load_bfrag(wv, HIDDEN, krow * 8 + 32 * s, ct * 16 + col);
            }
        for (int t = slot; t < NTILES; t += QKV_WPR) {
            int n0 = t * 16;
            const __half* ap = xh + (size_t)(n0 + col) * 320 + lx * 64 + krow * 8;
            h8 a0 = *(const h8*)(const void*)ap;
            h8 a1 = *(const h8*)(const void*)(ap + 32);
            f32x4 ak[4] = {{0.f, 0.f, 0.f, 0.f}, {0.f, 0.f, 0.f, 0.f},
                           {0.f, 0.f, 0.f, 0.f}, {0.f, 0.f, 0.f, 0.f}};
            f32x4 av[4] = {{0.f, 0.f, 0.f, 0.f}, {0.f, 0.f, 0.f, 0.f},
                           {0.f, 0.f, 0.f, 0.f}, {0.f, 0.f, 0.f, 0.f}};
#pragma unroll
            for (int ct = 0; ct < 4; ++ct) {
                ak[ct] = MFMA16(a0, Bk[ct][0], ak[ct]);
                ak[ct] = MFMA16(a1, Bk[ct][1], ak[ct]);
                av[ct] = MFMA16(a0, Bv[ct][0], av[ct]);
                av[ct] = MFMA16(a1, Bv[ct][1], av[ct]);
            }
#pragma unroll
            for (int ct = 0; ct < 4; ++ct)
#pragma unroll
                for (int reg = 0; reg < 4; ++reg) {
                    int n = n0 + krow * 4 + reg;
                    size_t base = ((size_t)n * L + lx) * 128 + ct * 16 + col;
                    kvi[base] = __float2half(ak[ct][reg]);
                    kvi[base + 64] = __float2half(av[ct][reg]);
                }
        }
    }
}

// CSR edge kernel, 8 edges per wave: subgroup g (8 lanes) owns edge base+g;
// lane r owns head r (channels 8r..8r+7). No cross-lane ops in the edge loop.
template <int L>
__global__ __launch_bounds__(256) void k_edge_csr8(const int* __restrict__ rowptr,
                                                   const int2* __restrict__ edata,
                                                   const __half* __restrict__ kvi,
                                                   const __half* __restrict__ qh,
                                                   float* __restrict__ aggout,
                                                   __half* __restrict__ xh) {
    int tid = threadIdx.x;
    int wid = tid >> 6, lane = tid & 63;
    int g = lane >> 3, r = lane & 7;
    int d = blockIdx.x * 4 + wid;
    if (d >= N_NODES) return;
    int rs = rowptr[d], re = rowptr[d + 1];
    float qf[8];
    unpack8(((const float4*)(qh + (size_t)d * 64))[r], qf);
    float acc[8];
#pragma unroll
    for (int i = 0; i < 8; ++i) acc[i] = 0.f;
    for (int base = rs; base < re; base += 8) {
        int eidx = base + g;
        bool valid = eidx < re;
        int2 e = edata[valid ? eidx : rs];
        int s = e.x;
        float nrm = valid ? __int_as_float(e.y) : 0.f;
        float sc[L];
        float4 vraw[L];
        const __half* kb = kvi + (size_t)s * (L * 128) + r * 8;
#pragma unroll
        for (int l = 0; l < L; ++l) {
            float4 kraw = *(const float4*)(kb + l * 128);
            vraw[l] = *(const float4*)(kb + l * 128 + 64);
            float kf[8];
            unpack8(kraw, kf);
            float p = 0.f;
#pragma unroll
            for (int c = 0; c < 8; ++c) p = fmaf(qf[c], kf[c], p);
            sc[l] = p;
        }
        float m = sc[0];
#pragma unroll
        for (int l = 1; l < L; ++l) m = fmaxf(m, sc[l]);
        float ssum = 0.f;
#pragma unroll
        for (int l = 0; l < L; ++l) { sc[l] = __expf(sc[l] - m); ssum += sc[l]; }
        float w = __fdividef(nrm, ssum);  // 0 for invalid lanes
#pragma unroll
        for (int l = 0; l < L; ++l) {
            float swl = sc[l] * w;
            float vf[8];
            unpack8(vraw[l], vf);
#pragma unroll
            for (int c = 0; c < 8; ++c) acc[c] = fmaf(swl, vf[c], acc[c]);
        }
    }
#pragma unroll
    for (int c = 0; c < 8; ++c) {
        acc[c] += __shfl_xor(acc[c], 8);
        acc[c] += __shfl_xor(acc[c], 16);
        acc[c] += __shfl_xor(acc[c], 32);
    }
    if (lane < 8) {  // g==0, r==lane
        if (L == NUM_LAYERS) {
            float4 o0, o1;
            o0.x = fmaxf(acc[0], 0.f); o0.y = fmaxf(acc[1], 0.f);
            o0.z = fmaxf(acc[2], 0.f); o0.w = fmaxf(acc[3], 0.f);
            o1.x = fmaxf(acc[4], 0.f); o1.y = fmaxf(acc[5], 0.f);
            o1.z = fmaxf(acc[6], 0.f); o1.w = fmaxf(acc[7], 0.f);
            float4* op = (float4*)(aggout + (size_t)d * 64 + r * 8);
            op[0] = o0; op[1] = o1;
        } else {
            __half hbuf[8];
#pragma unroll
            for (int c = 0; c < 8; ++c) hbuf[c] = __float2half(fmaxf(acc[c], 0.f));
            *(float4*)(xh + (size_t)d * 320 + L * 64 + r * 8) = *(float4*)hbuf;
        }
    }
}

// logits = aggout @ w2 + b2; out = log_softmax(logits)
__global__ __launch_bounds__(256) void k_final_lds(const float* __restrict__ aggout,
                                                   const float* __restrict__ w2,
                                                   const float* __restrict__ b2,
                                                   float* __restrict__ out) {
    __shared__ float rows[16][HIDDEN];
    int tid = threadIdx.x, wid = tid >> 6, lane = tid & 63;
    int cl = (lane < OUT_CH) ? lane : (OUT_CH - 1);
    float wcol[HIDDEN];
#pragma unroll
    for (int j = 0; j < HIDDEN; ++j) wcol[j] = w2[j * OUT_CH + cl];
    float b = b2[cl];
    for (int t = blockIdx.x; t < NTILES; t += gridDim.x) {
        int n0 = t * 16;
        {
            int rr = tid >> 4, seg = tid & 15;
            *(float4*)&rows[rr][seg * 4] =
                *(const float4*)&aggout[(size_t)(n0 + rr) * 64 + seg * 4];
        }
        __syncthreads();
#pragma unroll
        for (int u = 0; u < 4; ++u) {
            int ln = wid * 4 + u;
            const float4* rp = (const float4*)rows[ln];
            float a0 = 0.f, a1 = 0.f, a2 = 0.f, a3 = 0.f;
#pragma unroll
            for (int jc = 0; jc < HIDDEN / 4; ++jc) {
                float4 r = rp[jc];
                a0 = fmaf(r.x, wcol[jc * 4 + 0], a0);
                a1 = fmaf(r.y, wcol[jc * 4 + 1], a1);
                a2 = fmaf(r.z, wcol[jc * 4 + 2], a2);
                a3 = fmaf(r.w, wcol[jc * 4 + 3], a3);
            }
            float logit = (lane < OUT_CH) ? ((a0 + a1) + (a2 + a3) + b) : -INFINITY;
            float m = logit;
            for (int mask = 32; mask; mask >>= 1) m = fmaxf(m, __shfl_xor(m, mask));
            float ex = (lane < OUT_CH) ? __expf(logit - m) : 0.f;
            float ssum = ex;
            for (int mask = 32; mask; mask >>= 1) ssum += __shfl_xor(ssum, mask);
            if (lane < OUT_CH)
                out[(size_t)(n0 + ln) * OUT_CH + lane] = logit - m - logf(ssum);
        }
        __syncthreads();
    }
}

extern "C" void kernel_launch(void* const* d_in, const int* in_sizes, int n_in,
                              void* d_out, int out_size, void* d_ws, size_t ws_size,
                              hipStream_t stream) {
    const float* x  = (const float*)d_in[0];
    const int*   ei = (const int*)d_in[1];
    // d_in[2] = heads (known 8)
    const float* w1 = (const float*)d_in[3];
    const float* b1 = (const float*)d_in[4];
    const float* wq = (const float*)d_in[5];
    const float* wk = (const float*)d_in[6];
    const float* wv = (const float*)d_in[7];
    const float* w2 = (const float*)d_in[8];
    const float* b2 = (const float*)d_in[9];
    float* out = (float*)d_out;

    char* cur = (char*)d_ws;
    auto alloc = [&](size_t bytes) { char* p = cur; cur += (bytes + 255) & ~(size_t)255; return p; };
    float*   dinv   = (float*)alloc(N_NODES * 4);
    __half*  xh     = (__half*)alloc((size_t)N_NODES * 320 * 2);
    float*   aggout = (float*)alloc((size_t)N_NODES * 64 * 4);
    __half*  qh     = (__half*)alloc((size_t)N_NODES * 64 * 2);
    __half*  kvi    = (__half*)alloc((size_t)N_NODES * NUM_LAYERS * 128 * 2);
    __half*  vh1    = (__half*)alloc((size_t)N_NODES * 64 * 2);
    int*     count  = (int*)alloc(N_NODES * 4);
    int*     loc    = (int*)alloc(N_NODES * 4);
    int*     psum   = (int*)alloc(256 * 4);
    int*     rowptr = (int*)alloc((N_NODES + 1) * 4);
    int*     fill   = (int*)alloc(N_NODES * 4);
    int2*    edata  = (int2*)alloc((size_t)E_TOT * 8);

    // CSR build (once)
    k_count_init<<<(N_NODES + 255) / 256, 256, 0, stream>>>(count, fill);
    k_count<<<(N_EDGES + 255) / 256, 256, 0, stream>>>(ei + N_EDGES, count);
    k_scan_a<<<NCHUNK, 256, 0, stream>>>(count, loc, psum);
    k_scan_b<<<1, 256, 0, stream>>>(psum);
    k_scan_c<<<(N_NODES + 255) / 256, 256, 0, stream>>>(count, loc, psum, rowptr,
                                                        dinv, edata);
    k_scatter<<<(N_EDGES + 255) / 256, 256, 0, stream>>>(ei, rowptr, fill, dinv, edata);

    k_h_mfma<<<256, 256, 0, stream>>>(x, w1, b1, xh);

    // Layer 1 (L=1): softmax over a single slot == 1; only v matters.
    k_v1_mfma<<<QKV_WPR / 4, 256, 0, stream>>>(xh, wv, vh1);
    k_edge_l1<<<(N_NODES + 3) / 4, 256, 0, stream>>>(rowptr, edata, vh1, xh);

    for (int i = 1; i < NUM_LAYERS; ++i) {
        int L = i + 1;
        int qkvblk = (L + 1) * (QKV_WPR / 4);
        const float* wqi = wq + i * 4096;
        const float* wki = wk + i * 4096;
        const float* wvi = wv + i * 4096;
        switch (L) {
            case 2:
                k_qkv_mfma<2><<<qkvblk, 256, 0, stream>>>(xh, wqi, wki, wvi, qh, kvi);
                k_edge_csr8<2><<<(N_NODES + 3) / 4, 256, 0, stream>>>(rowptr, edata, kvi, qh, aggout, xh);
                break;
            case 3:
                k_qkv_mfma<3><<<qkvblk, 256, 0, stream>>>(xh, wqi, wki, wvi, qh, kvi);
                k_edge_csr8<3><<<(N_NODES + 3) / 4, 256, 0, stream>>>(rowptr, edata, kvi, qh, aggout, xh);
                break;
            default:
                k_qkv_mfma<4><<<qkvblk, 256, 0, stream>>>(xh, wqi, wki, wvi, qh, kvi);
                k_edge_csr8<4><<<(N_NODES + 3) / 4, 256, 0, stream>>>(rowptr, edata, kvi, qh, aggout, xh);
                break;
        }
    }
    k_final_lds<<<512, 256, 0, stream>>>(aggout, w2, b2, out);
}